// Round 1
// baseline (108.574 us; speedup 1.0000x reference)
//
#include <hip/hip_runtime.h>
#include <hip/hip_bf16.h>

// Problem constants (fixed by setup_inputs)
#define B_N     64
#define C_ORIG  448
#define C_SEL   100
#define CP      128      // padded channel count (bf16, K-dim for MFMA)
#define HW      3136     // 56*56
#define IMG     224

typedef short bf16x8 __attribute__((ext_vector_type(8)));
typedef float f32x4  __attribute__((ext_vector_type(4)));

static __device__ __forceinline__ unsigned short f2bf(float f) {
    // round-to-nearest-even f32 -> bf16
    unsigned int u = __float_as_uint(f);
    unsigned int r = (u + 0x7FFFu + ((u >> 16) & 1u)) >> 16;
    return (unsigned short)r;
}

// ---------------------------------------------------------------------------
// Kernel A: gather selected channels, subtract mean, bf16-cast, transpose to
// D[p][b][c] with c padded to 128 (pad = 0.0 for MFMA K-padding).
// grid (49, 64): blockIdx.x = p-tile of 64, blockIdx.y = b. 256 threads.
// ---------------------------------------------------------------------------
__global__ __launch_bounds__(256) void kA_gather(const float* __restrict__ feats,
                                                 const float* __restrict__ mean,
                                                 const int* __restrict__ sel,
                                                 unsigned short* __restrict__ D)
{
    __shared__ float mean_s[64 * 105];          // stride 105 -> conflict-free
    __shared__ unsigned short Dt[64 * 128];     // 16 KB transpose tile, XOR-swizzled

    const int tid = threadIdx.x;
    const int p0  = blockIdx.x * 64;
    const int b   = blockIdx.y;

    // phase 0: zero Dt (provides zero K-padding c=100..127)
    {
        uint4 z = make_uint4(0u, 0u, 0u, 0u);
        uint4* dst = reinterpret_cast<uint4*>(Dt);
#pragma unroll
        for (int q = 0; q < 4; ++q) dst[tid + q * 256] = z;   // 1024 * 16B = 16KB
    }
    // phase 1: mean rows p0..p0+63 -> LDS (contiguous 6400 floats, re-strided 100->105)
    {
        const float4* src = reinterpret_cast<const float4*>(mean + (size_t)p0 * C_SEL);
#pragma unroll
        for (int q = 0; q < 7; ++q) {
            int idx4 = tid + q * 256;
            if (idx4 < 1600) {
                float4 v = src[idx4];
                int p = (idx4 * 4) / C_SEL;
                int c = (idx4 * 4) % C_SEL;
                float* d = &mean_s[p * 105 + c];
                d[0] = v.x; d[1] = v.y; d[2] = v.z; d[3] = v.w;
            }
        }
    }
    __syncthreads();

    // phase 2: each wave covers a c-range; lane = local p. Coalesced 256B feats reads.
    {
        const int w    = tid >> 6;
        const int lane = tid & 63;
        const int cbase = w * 26;
        const int ccnt  = (w < 3) ? 26 : 22;                 // 26+26+26+22 = 100
        const float* fb = feats + (size_t)b * (C_ORIG * HW) + p0 + lane;
        for (int cc = 0; cc < ccnt; cc += 2) {
            int c0  = cbase + cc;
            int ch0 = sel[c0];
            int ch1 = sel[c0 + 1];
            float v0 = fb[ch0 * HW] - mean_s[lane * 105 + c0];
            float v1 = fb[ch1 * HW] - mean_s[lane * 105 + c0 + 1];
            unsigned int pk = (unsigned int)f2bf(v0) | ((unsigned int)f2bf(v1) << 16);
            // swizzled write: row = lane(p), byte-in-row = 2c XOR ((p&7)<<4)
            int byte = lane * 256 + ((2 * c0) ^ ((lane & 7) << 4));
            *reinterpret_cast<unsigned int*>(reinterpret_cast<char*>(Dt) + byte) = pk;
        }
    }
    __syncthreads();

    // phase 3: un-swizzle, write D[p][b][0..127] as 16B slots (fully coalesced rows)
    {
        unsigned short* Dp = D + (size_t)p0 * (B_N * CP) + (size_t)b * CP;
#pragma unroll
        for (int q = 0; q < 4; ++q) {
            int unit = tid + q * 256;     // 0..1023
            int p = unit >> 4;            // local p 0..63
            int s = unit & 15;            // c-octet 0..15
            int u = s ^ (p & 7);          // swizzled slot holding octet s
            uint4 val = *reinterpret_cast<const uint4*>(
                reinterpret_cast<const char*>(Dt) + p * 256 + u * 16);
            *reinterpret_cast<uint4*>(
                reinterpret_cast<char*>(Dp) + (size_t)p * (B_N * CP * 2) + s * 16) = val;
        }
    }
}

// ---------------------------------------------------------------------------
// Kernel B: per-pixel Mahalanobis via MFMA.  Z = M (100x128, A-op, LDS bf16
// swizzled) x D^T (B-op, straight from global), dist[b] = sum_i D[b,i]*Z[i,b].
// grid 3136 blocks (one per p), 256 threads = 4 waves; wave w owns b-tile w.
// ---------------------------------------------------------------------------
__global__ __launch_bounds__(256) void kB_maha(const float* __restrict__ icov,
                                               const unsigned short* __restrict__ D,
                                               float* __restrict__ dist)
{
    __shared__ unsigned short Mb[112 * 128];   // 28672 B, XOR-swizzled rows

    const int tid = threadIdx.x;
    const int p   = blockIdx.x;

    // zero Mb (K-pad + rows 100..111 stay finite)
    {
        uint4 z = make_uint4(0u, 0u, 0u, 0u);
        uint4* dst = reinterpret_cast<uint4*>(Mb);
#pragma unroll
        for (int q = 0; q < 7; ++q) dst[tid + q * 256] = z;   // 1792 * 16B = 28672B
    }
    __syncthreads();

    // stage icov[p] -> bf16 LDS (coalesced float4 reads, swizzled 8B writes)
    {
        const float4* src = reinterpret_cast<const float4*>(icov + (size_t)p * (C_SEL * C_SEL));
#pragma unroll
        for (int q = 0; q < 10; ++q) {
            int idx4 = tid + q * 256;
            if (idx4 < 2500) {
                float4 v = src[idx4];
                int i  = idx4 / 25;
                int j4 = (idx4 % 25) * 4;
                unsigned int lo = (unsigned int)f2bf(v.x) | ((unsigned int)f2bf(v.y) << 16);
                unsigned int hi = (unsigned int)f2bf(v.z) | ((unsigned int)f2bf(v.w) << 16);
                int byte = i * 256 + ((2 * j4) ^ ((i & 7) << 4));
                *reinterpret_cast<uint2*>(reinterpret_cast<char*>(Mb) + byte) = make_uint2(lo, hi);
            }
        }
    }
    __syncthreads();

    const int w    = tid >> 6;
    const int lane = tid & 63;
    const int lrow = lane & 15;
    const int g    = lane >> 4;
    const int bcol = w * 16 + lrow;
    const unsigned short* Dp = D + (size_t)p * (B_N * CP);

    f32x4 acc[7];
#pragma unroll
    for (int it = 0; it < 7; ++it) acc[it] = (f32x4){0.f, 0.f, 0.f, 0.f};

#pragma unroll
    for (int ks = 0; ks < 4; ++ks) {
        const int k0 = ks * 32;
        // B operand: lane holds D[bcol][k0 + g*8 .. +8]; 16 fully-used 64B lines/wave
        bf16x8 bfrag = *reinterpret_cast<const bf16x8*>(Dp + (size_t)bcol * CP + k0 + g * 8);
#pragma unroll
        for (int it = 0; it < 7; ++it) {
            int i = it * 16 + lrow;
            int byte = i * 256 + (((k0 * 2) + g * 16) ^ ((i & 7) << 4));
            bf16x8 afrag = *reinterpret_cast<const bf16x8*>(
                reinterpret_cast<const char*>(Mb) + byte);
            acc[it] = __builtin_amdgcn_mfma_f32_16x16x32_bf16(afrag, bfrag, acc[it], 0, 0, 0);
        }
    }

    // epilogue: dist[b] = sum_i D[b,i] * Z[i,b]; C/D layout col=lane&15,row=g*4+r
    float partial = 0.f;
#pragma unroll
    for (int it = 0; it < 7; ++it) {
#pragma unroll
        for (int r = 0; r < 4; ++r) {
            int i = it * 16 + g * 4 + r;
            if (i < C_SEL) {
                unsigned int dv = ((unsigned int)Dp[(size_t)bcol * CP + i]) << 16;
                partial += acc[it][r] * __uint_as_float(dv);
            }
        }
    }
    partial += __shfl_xor(partial, 16);
    partial += __shfl_xor(partial, 32);
    if (g == 0) dist[p * B_N + bcol] = partial;   // layout dist[p][b], 256B/block
}

// ---------------------------------------------------------------------------
// Kernel C: bilinear 56 -> 224 (jax half-pixel: src = d*0.25 - 0.375, edge
// renormalization == clamp).  grid 64*224 blocks, thread = x.
// ---------------------------------------------------------------------------
__global__ __launch_bounds__(256) void kC_resize(const float* __restrict__ dist,
                                                 float* __restrict__ out)
{
    const int bid = blockIdx.x;          // 0..14335
    const int b = bid / IMG;
    const int y = bid % IMG;
    const int x = threadIdx.x;
    if (x >= IMG) return;

    float sy = y * 0.25f - 0.375f;
    float fy0 = floorf(sy);
    float fy = sy - fy0;
    int y0 = (int)fy0, y1 = y0 + 1;
    y0 = max(y0, 0); y1 = min(y1, 55);

    float sx = x * 0.25f - 0.375f;
    float fx0 = floorf(sx);
    float fx = sx - fx0;
    int x0 = (int)fx0, x1 = x0 + 1;
    x0 = max(x0, 0); x1 = min(x1, 55);

    float d00 = dist[(y0 * 56 + x0) * B_N + b];
    float d01 = dist[(y0 * 56 + x1) * B_N + b];
    float d10 = dist[(y1 * 56 + x0) * B_N + b];
    float d11 = dist[(y1 * 56 + x1) * B_N + b];
    float top = d00 + fx * (d01 - d00);
    float bot = d10 + fx * (d11 - d10);
    out[((size_t)b * IMG + y) * IMG + x] = top + fy * (bot - top);
}

extern "C" void kernel_launch(void* const* d_in, const int* in_sizes, int n_in,
                              void* d_out, int out_size, void* d_ws, size_t ws_size,
                              hipStream_t stream)
{
    const float* feats = (const float*)d_in[0];
    const float* mean  = (const float*)d_in[1];
    const float* icov  = (const float*)d_in[2];
    const int*   sel   = (const int*)d_in[3];    // jax default x64-off -> int32
    float* out = (float*)d_out;

    unsigned short* Dws = (unsigned short*)d_ws;                 // 3136*64*128*2B = 51.4MB
    float* distws = (float*)((char*)d_ws + (size_t)HW * B_N * CP * 2); // +803KB

    dim3 gA(49, B_N);
    kA_gather<<<gA, 256, 0, stream>>>(feats, mean, sel, Dws);
    kB_maha<<<HW, 256, 0, stream>>>(icov, Dws, distws);
    kC_resize<<<B_N * IMG, 256, 0, stream>>>(distws, out);
}

// Round 2
// 87.217 us; speedup vs baseline: 1.2449x; 1.2449x over previous
//
#include <hip/hip_runtime.h>
#include <hip/hip_bf16.h>

// Problem constants (fixed by setup_inputs)
#define B_N     64
#define C_ORIG  448
#define C_SEL   100
#define CP      128      // padded channel count (bf16, K-dim for MFMA)
#define HW      3136     // 56*56
#define IMG     224

typedef short bf16x8 __attribute__((ext_vector_type(8)));
typedef float f32x4  __attribute__((ext_vector_type(4)));

static __device__ __forceinline__ unsigned short f2bf(float f) {
    // round-to-nearest-even f32 -> bf16
    unsigned int u = __float_as_uint(f);
    return (unsigned short)((u + 0x7FFFu + ((u >> 16) & 1u)) >> 16);
}
static __device__ __forceinline__ float bf2f(unsigned short h) {
    return __uint_as_float(((unsigned int)h) << 16);
}

// ---------------------------------------------------------------------------
// Kernel A: gather selected channels, subtract mean (direct from L2), bf16,
// transpose to D[p][b][c] (c padded to 128 with zeros).
// LDS: 16KB transpose tile only -> 8 blocks/CU. One barrier total.
// Swizzle: 8B unit u of row p lives at byte (8u)^((p&31)<<3).
//   - writes (lane=p varies, u fixed): banks spread by lane&15 -> min cycles
//   - b128 readback: 16B slot s at (16s)^(swz&0xF0); odd p swaps halves
// ---------------------------------------------------------------------------
__global__ __launch_bounds__(256) void kA_gather(const float* __restrict__ feats,
                                                 const float* __restrict__ mean,
                                                 const int* __restrict__ sel,
                                                 unsigned short* __restrict__ D)
{
    __shared__ unsigned short Dt[64 * 128];   // 16 KB
    char* DtB = reinterpret_cast<char*>(Dt);
    const int tid = threadIdx.x;
    const int p0  = blockIdx.x * 64;
    const int b   = blockIdx.y;

    // zero pad units (rows 0..63, units 25..31) — bytes disjoint from data
#pragma unroll
    for (int q = 0; q < 2; ++q) {
        int z = tid + q * 256;
        if (z < 448) {
            int pr = z / 7, un = 25 + z % 7;
            *reinterpret_cast<uint2*>(DtB + pr * 256 + ((8 * un) ^ ((pr & 31) << 3)))
                = make_uint2(0u, 0u);
        }
    }

    const int w    = tid >> 6;
    const int lane = tid & 63;
    const float* fb   = feats + (size_t)b * (C_ORIG * HW) + p0 + lane;
    const float* mrow = mean + (size_t)(p0 + lane) * C_SEL;
    const unsigned swz = (unsigned)(lane & 31) << 3;
    char* rowB = DtB + lane * 256;

    auto quad = [&](int c0) {
        int ch0 = sel[c0], ch1 = sel[c0 + 1], ch2 = sel[c0 + 2], ch3 = sel[c0 + 3];
        float4 m4 = *reinterpret_cast<const float4*>(mrow + c0);
        float v0 = fb[(size_t)ch0 * HW] - m4.x;
        float v1 = fb[(size_t)ch1 * HW] - m4.y;
        float v2 = fb[(size_t)ch2 * HW] - m4.z;
        float v3 = fb[(size_t)ch3 * HW] - m4.w;
        uint2 pk = make_uint2((unsigned)f2bf(v0) | ((unsigned)f2bf(v1) << 16),
                              (unsigned)f2bf(v2) | ((unsigned)f2bf(v3) << 16));
        *reinterpret_cast<uint2*>(rowB + (((unsigned)(2 * c0)) ^ swz)) = pk;
    };

    if (w < 3) {
#pragma unroll
        for (int q = 0; q < 6; ++q) quad(w * 24 + q * 4);   // waves 0-2: 24 ch
    } else {
#pragma unroll
        for (int q = 0; q < 7; ++q) quad(72 + q * 4);       // wave 3: 28 ch
    }
    __syncthreads();

    // un-swizzle + write D rows (16B per thread-unit, fully coalesced)
    unsigned short* Dp = D + (size_t)p0 * (B_N * CP) + (size_t)b * CP;
#pragma unroll
    for (int q = 0; q < 4; ++q) {
        int unit = tid + q * 256;       // 0..1023
        int pr = unit >> 4;             // local p
        int s  = unit & 15;             // 16B slot
        unsigned off = ((unsigned)(16 * s)) ^ ((((unsigned)pr & 31u) << 3) & 0xF0u);
        uint4 v = *reinterpret_cast<const uint4*>(DtB + pr * 256 + off);
        uint4 r = (pr & 1) ? make_uint4(v.z, v.w, v.x, v.y) : v;
        *reinterpret_cast<uint4*>(reinterpret_cast<char*>(Dp)
            + (size_t)pr * (B_N * CP * 2) + s * 16) = r;
    }
}

// ---------------------------------------------------------------------------
// Kernel B: per-pixel Mahalanobis via MFMA. Z = M(100x128, LDS bf16 swizzled)
// x D^T (global, hoisted to regs), dist[b] = sum_i D[b,i]*Z[i,b].
// One barrier per block; pad-zeroing disjoint from staged data; B-frags +
// epilogue D-chunks loaded before staging so they hide under the icov stream.
// ---------------------------------------------------------------------------
__global__ __launch_bounds__(256) void kB_maha(const float* __restrict__ icov,
                                               const unsigned short* __restrict__ D,
                                               float* __restrict__ dist)
{
    __shared__ unsigned short Mb[112 * 128];   // 28672 B, slot-swizzle ((i&7)<<4)
    char* MbB = reinterpret_cast<char*>(Mb);
    const int tid = threadIdx.x;
    const int p   = blockIdx.x;
    const int w    = tid >> 6;
    const int lane = tid & 63;
    const int lrow = lane & 15;
    const int g    = lane >> 4;
    const int bcol = w * 16 + lrow;
    const unsigned short* Drow = D + (size_t)p * (B_N * CP) + (size_t)bcol * CP;

    // hoist all D reads (fly under icov staging)
    bf16x8 bfr[4];
#pragma unroll
    for (int ks = 0; ks < 4; ++ks)
        bfr[ks] = *reinterpret_cast<const bf16x8*>(Drow + ks * 32 + g * 8);
    ushort4 dvec[7];
#pragma unroll
    for (int it = 0; it < 7; ++it)
        dvec[it] = *reinterpret_cast<const ushort4*>(Drow + it * 16 + g * 4);

    // pad zeros: rows 0..99 units 25..31 (700 uint2)
#pragma unroll
    for (int q = 0; q < 3; ++q) {
        int z = tid + q * 256;
        if (z < 700) {
            int i = z / 7, un = 25 + z % 7;
            *reinterpret_cast<uint2*>(MbB + i * 256 + ((8 * un) ^ ((i & 7) << 4)))
                = make_uint2(0u, 0u);
        }
    }
    // pad zeros: rows 100..111 full (384 uint2)
#pragma unroll
    for (int q = 0; q < 2; ++q) {
        int z = tid + q * 256;
        if (z < 384) {
            int i = 100 + (z >> 5), un = z & 31;
            *reinterpret_cast<uint2*>(MbB + i * 256 + ((8 * un) ^ ((i & 7) << 4)))
                = make_uint2(0u, 0u);
        }
    }
    // stage icov[p] -> bf16 LDS (coalesced float4 reads, swizzled 8B writes)
    const float4* src = reinterpret_cast<const float4*>(icov + (size_t)p * (C_SEL * C_SEL));
#pragma unroll
    for (int q = 0; q < 10; ++q) {
        int idx4 = tid + q * 256;
        if (idx4 < 2500) {
            float4 v = src[idx4];
            int i = idx4 / 25, un = idx4 % 25;
            uint2 pk = make_uint2((unsigned)f2bf(v.x) | ((unsigned)f2bf(v.y) << 16),
                                  (unsigned)f2bf(v.z) | ((unsigned)f2bf(v.w) << 16));
            *reinterpret_cast<uint2*>(MbB + i * 256 + ((8 * un) ^ ((i & 7) << 4))) = pk;
        }
    }
    __syncthreads();

    f32x4 acc[7];
#pragma unroll
    for (int it = 0; it < 7; ++it) acc[it] = (f32x4){0.f, 0.f, 0.f, 0.f};

#pragma unroll
    for (int ks = 0; ks < 4; ++ks) {
#pragma unroll
        for (int it = 0; it < 7; ++it) {
            int i = it * 16 + lrow;
            bf16x8 afrag = *reinterpret_cast<const bf16x8*>(
                MbB + i * 256 + ((ks * 64 + g * 16) ^ ((i & 7) << 4)));
            acc[it] = __builtin_amdgcn_mfma_f32_16x16x32_bf16(afrag, bfr[ks], acc[it], 0, 0, 0);
        }
    }

    // epilogue: dist[b] = sum_i D[b,i] * Z[i,b]; C/D layout col=lane&15, row=g*4+r
    float partial = 0.f;
#pragma unroll
    for (int it = 0; it < 7; ++it) {
#pragma unroll
        for (int r = 0; r < 4; ++r) {
            int i = it * 16 + g * 4 + r;
            if (i < C_SEL) {
                unsigned short dh = (r == 0) ? dvec[it].x : (r == 1) ? dvec[it].y
                                   : (r == 2) ? dvec[it].z : dvec[it].w;
                partial += acc[it][r] * bf2f(dh);
            }
        }
    }
    partial += __shfl_xor(partial, 16);
    partial += __shfl_xor(partial, 32);
    if (g == 0) dist[p * B_N + bcol] = partial;   // dist[p][b]
}

// ---------------------------------------------------------------------------
// Kernel C: bilinear 56 -> 224. 4 outputs per thread (x weights are static:
// fx = .625/.875/.125/.375 over src cells m-1,m,m+1). float4 stores.
// ---------------------------------------------------------------------------
__global__ __launch_bounds__(256) void kC_resize(const float* __restrict__ dist,
                                                 float* __restrict__ out)
{
    int gid = blockIdx.x * 256 + threadIdx.x;   // 802816 = 64*224*56 exactly
    int m = gid % 56;
    int t = gid / 56;
    int y = t % IMG;
    int b = t / IMG;

    float sy = y * 0.25f - 0.375f;
    float fy0 = floorf(sy);
    float fy = sy - fy0;
    int y0 = max((int)fy0, 0);
    int y1 = min((int)fy0 + 1, 55);
    int xm1 = max(m - 1, 0);
    int xp1 = min(m + 1, 55);

    const float* d0 = dist + (y0 * 56) * B_N + b;
    const float* d1 = dist + (y1 * 56) * B_N + b;
    float a0 = d0[xm1 * B_N], b0 = d0[m * B_N], c0 = d0[xp1 * B_N];
    float a1 = d1[xm1 * B_N], b1 = d1[m * B_N], c1 = d1[xp1 * B_N];

    float A  = a0 + fy * (a1 - a0);
    float Bv = b0 + fy * (b1 - b0);
    float Cv = c0 + fy * (c1 - c0);

    float4 o;
    o.x = A  + 0.625f * (Bv - A);    // x=4m:   x0=m-1, fx=0.625
    o.y = A  + 0.875f * (Bv - A);    // x=4m+1: fx=0.875
    o.z = Bv + 0.125f * (Cv - Bv);   // x=4m+2: x0=m,   fx=0.125
    o.w = Bv + 0.375f * (Cv - Bv);   // x=4m+3: fx=0.375
    *reinterpret_cast<float4*>(out + ((size_t)b * IMG + y) * IMG + 4 * m) = o;
}

extern "C" void kernel_launch(void* const* d_in, const int* in_sizes, int n_in,
                              void* d_out, int out_size, void* d_ws, size_t ws_size,
                              hipStream_t stream)
{
    const float* feats = (const float*)d_in[0];
    const float* mean  = (const float*)d_in[1];
    const float* icov  = (const float*)d_in[2];
    const int*   sel   = (const int*)d_in[3];
    float* out = (float*)d_out;

    unsigned short* Dws = (unsigned short*)d_ws;                        // 51.4 MB
    float* distws = (float*)((char*)d_ws + (size_t)HW * B_N * CP * 2);  // +803 KB

    dim3 gA(49, B_N);
    kA_gather<<<gA, 256, 0, stream>>>(feats, mean, sel, Dws);
    kB_maha<<<HW, 256, 0, stream>>>(icov, Dws, distws);
    kC_resize<<<3136, 256, 0, stream>>>(distws, out);
}